// Round 1
// baseline (1778.108 us; speedup 1.0000x reference)
//
#include <hip/hip_runtime.h>

constexpr int NN = 100000;   // nodes
constexpr int EE = 3200000;  // edges
constexpr int GG = 5000;     // graphs
constexpr float BNEPS = 1e-5f;

constexpr int SCAN_BLK = 256;
constexpr int SCAN_ITEMS = 1024;                       // 256 thr x 4
constexpr int NSCANBLK = (NN + SCAN_ITEMS - 1) / SCAN_ITEMS;  // 98

// ---------------- CSR build ----------------

__global__ void count_kernel(const int* __restrict__ ei, int* __restrict__ cnt) {
    int e = blockIdx.x * blockDim.x + threadIdx.x;
    if (e < EE) atomicAdd(&cnt[ei[EE + e]], 1);
}

__global__ void scanA(const int* __restrict__ cnt, int* __restrict__ bsum) {
    __shared__ int ls[SCAN_BLK];
    int t = threadIdx.x;
    int base = blockIdx.x * SCAN_ITEMS + t * 4;
    int s = 0;
#pragma unroll
    for (int k = 0; k < 4; ++k) { int i = base + k; if (i < NN) s += cnt[i]; }
    ls[t] = s; __syncthreads();
    for (int off = 128; off > 0; off >>= 1) {
        if (t < off) ls[t] += ls[t + off];
        __syncthreads();
    }
    if (t == 0) bsum[blockIdx.x] = ls[0];
}

__global__ void scanB(const int* __restrict__ bsum, int* __restrict__ boff) {
    __shared__ int ls[SCAN_BLK];
    int t = threadIdx.x;
    int v = (t < NSCANBLK) ? bsum[t] : 0;
    ls[t] = v; __syncthreads();
    for (int off = 1; off < SCAN_BLK; off <<= 1) {
        int x = 0;
        if (t >= off) x = ls[t - off];
        __syncthreads();
        ls[t] += x;
        __syncthreads();
    }
    if (t < NSCANBLK) boff[t] = ls[t] - v;  // exclusive
}

__global__ void scanC(int* __restrict__ cnt /* becomes fill-start */, const int* __restrict__ boff,
                      int* __restrict__ rowptr, float* __restrict__ dinv) {
    __shared__ int ls[SCAN_BLK];
    int t = threadIdx.x;
    int base = blockIdx.x * SCAN_ITEMS + t * 4;
    int c[4]; int s = 0;
#pragma unroll
    for (int k = 0; k < 4; ++k) { int i = base + k; c[k] = (i < NN) ? cnt[i] : 0; s += c[k]; }
    ls[t] = s; __syncthreads();
    for (int off = 1; off < SCAN_BLK; off <<= 1) {
        int x = 0;
        if (t >= off) x = ls[t - off];
        __syncthreads();
        ls[t] += x;
        __syncthreads();
    }
    int run = boff[blockIdx.x] + ls[t] - s;  // exclusive base for this thread
#pragma unroll
    for (int k = 0; k < 4; ++k) {
        int i = base + k;
        if (i < NN) {
            rowptr[i] = run;
            cnt[i] = run;  // fill cursor for scatter
            dinv[i] = rsqrtf((float)(c[k] + 1));  // +1 self-loop
            run += c[k];
            if (i == NN - 1) rowptr[NN] = run;
        }
    }
}

__global__ void scatter_kernel(const int* __restrict__ ei, int* __restrict__ fill,
                               int* __restrict__ colA) {
    int e = blockIdx.x * blockDim.x + threadIdx.x;
    if (e < EE) {
        int d = ei[EE + e];
        int pos = atomicAdd(&fill[d], 1);
        colA[pos] = ei[e];
    }
}

// ---------------- GEMM with fused BN-affine+ReLU on input, x dinv on output ----------------

template <int FIN, int FOUT, bool AFFINE>
__global__ void gemm_bn(const float* __restrict__ hin, const float* __restrict__ aArr,
                        const float* __restrict__ bArr, const float* __restrict__ W,
                        const float* __restrict__ dinv, float* __restrict__ hout) {
    constexpr int NB = 256 / FOUT;  // nodes per group
    __shared__ float Wl[FIN * FOUT];
    __shared__ float rows[NB][FIN];
    const int t = threadIdx.x;
    for (int i = t; i < FIN * FOUT; i += 256) Wl[i] = W[i];
    const int c = t % FOUT, s = t / FOUT;
    const int ngrp = (NN + NB - 1) / NB;
    for (int grp = blockIdx.x; grp < ngrp; grp += gridDim.x) {
        __syncthreads();  // covers Wl on first iter; protects rows reuse after
        for (int i = t; i < NB * FIN; i += 256) {
            int sn = i / FIN, k = i % FIN;
            int n2 = grp * NB + sn;
            float v = 0.f;
            if (n2 < NN) {
                v = hin[(size_t)n2 * FIN + k];
                if constexpr (AFFINE) {
                    v = aArr[k] * v + bArr[k];
                    v = v > 0.f ? v : 0.f;
                }
            }
            rows[sn][k] = v;
        }
        __syncthreads();
        int node = grp * NB + s;
        if (node < NN) {
            float acc = 0.f;
#pragma unroll
            for (int k = 0; k < FIN; ++k) acc += rows[s][k] * Wl[k * FOUT + c];
            hout[(size_t)node * FOUT + c] = acc * dinv[node];
        }
    }
}

// ---------------- gather aggregation: out[i] = dinv[i]*(h2s[i] + sum_nbr h2s[j]) + b ----------------

template <int F>
__global__ void agg_kernel(const float* __restrict__ h2s, const int* __restrict__ rowptr,
                           const int* __restrict__ colA, const float* __restrict__ dinv,
                           const float* __restrict__ bias, float* __restrict__ out) {
    constexpr int SUB = 64 / F;
    const int lane = threadIdx.x & 63;
    const int wid = (blockIdx.x * blockDim.x + threadIdx.x) >> 6;
    const int totalWaves = (gridDim.x * blockDim.x) >> 6;
    const int f = lane % F;
    const int sub = lane / F;
    const int stride = totalWaves * SUB;
    const float bi = bias[f];
    for (int i = wid * SUB + sub; i < NN; i += stride) {
        const int r0 = rowptr[i], r1 = rowptr[i + 1];
        float acc = h2s[(size_t)i * F + f];  // self loop term (already * dinv[i])
        for (int e = r0; e < r1; ++e) {
            int j = colA[e];
            acc += h2s[(size_t)j * F + f];
        }
        out[(size_t)i * F + f] = dinv[i] * acc + bi;
    }
}

// ---------------- BN stats ----------------

template <int F>
__global__ void bn_stats(const float* __restrict__ h, float* __restrict__ sums,
                         float* __restrict__ ssq) {
    __shared__ float ls[F], lq[F];
    const int t = threadIdx.x;
    const int c = t % F;
    constexpr int ROWS = 256 / F;
    float s = 0.f, q = 0.f;
    for (int n = blockIdx.x * ROWS + t / F; n < NN; n += gridDim.x * ROWS) {
        float v = h[(size_t)n * F + c];
        s += v; q += v * v;
    }
    if (t < F) { ls[t] = 0.f; lq[t] = 0.f; }
    __syncthreads();
    atomicAdd(&ls[c], s);
    atomicAdd(&lq[c], q);
    __syncthreads();
    if (t < F) { atomicAdd(&sums[t], ls[t]); atomicAdd(&ssq[t], lq[t]); }
}

template <int F>
__global__ void bn_finalize(const float* __restrict__ sums, const float* __restrict__ ssq,
                            const float* __restrict__ g, const float* __restrict__ be,
                            float* __restrict__ aArr, float* __restrict__ bArr) {
    int c = threadIdx.x;
    if (c < F) {
        float mu = sums[c] / (float)NN;
        float var = ssq[c] / (float)NN - mu * mu;
        float a = g[c] * rsqrtf(var + BNEPS);
        aArr[c] = a;
        bArr[c] = be[c] - mu * a;
    }
}

// ---------------- GAT: xg = relu(bn(out3)) @ Wg ; a_src/a_dst ----------------

__global__ void gat_pre(const float* __restrict__ out3, const float* __restrict__ aArr,
                        const float* __restrict__ bArr, const float* __restrict__ Wg,
                        const float* __restrict__ att_src, const float* __restrict__ att_dst,
                        float* __restrict__ xg, float* __restrict__ asrc,
                        float* __restrict__ adst) {
    __shared__ float Wl[16 * 128];
    __shared__ float row[2][16];
    __shared__ float red[2][128];
    const int t = threadIdx.x;
    for (int i = t; i < 16 * 128; i += 256) Wl[i] = Wg[i];
    const int c = t & 127, s = t >> 7;
    const float atts = att_src[c], attd = att_dst[c];
    const int h = c >> 4, cc = c & 15;
    const int ngrp = (NN + 1) / 2;
    for (int grp = blockIdx.x; grp < ngrp; grp += gridDim.x) {
        __syncthreads();
        if (t < 32) {
            int sn = t >> 4, k = t & 15;
            int n2 = grp * 2 + sn;
            float v = 0.f;
            if (n2 < NN) {
                v = out3[n2 * 16 + k];
                v = aArr[k] * v + bArr[k];
                v = v > 0.f ? v : 0.f;
            }
            row[sn][k] = v;
        }
        __syncthreads();
        float acc = 0.f;
#pragma unroll
        for (int k = 0; k < 16; ++k) acc += row[s][k] * Wl[k * 128 + c];
        int node = grp * 2 + s;
        if (node < NN) xg[(size_t)node * 128 + c] = acc;
        red[s][c] = acc * atts;
        __syncthreads();
        if (cc == 0 && node < NN) {
            float v = 0.f;
#pragma unroll
            for (int k2 = 0; k2 < 16; ++k2) v += red[s][h * 16 + k2];
            asrc[node * 8 + h] = v;
        }
        __syncthreads();
        red[s][c] = acc * attd;
        __syncthreads();
        if (cc == 0 && node < NN) {
            float v = 0.f;
#pragma unroll
            for (int k2 = 0; k2 < 16; ++k2) v += red[s][h * 16 + k2];
            adst[node * 8 + h] = v;
        }
    }
}

// ---------------- GAT segment-softmax + aggregation, one wave per node ----------------

__device__ __forceinline__ float leaky02(float x) { return x > 0.f ? x : 0.2f * x; }

__global__ void gat_agg(const float* __restrict__ xg, const float* __restrict__ asrc,
                        const float* __restrict__ adst, const int* __restrict__ rowptr,
                        const int* __restrict__ colA, const float* __restrict__ bg,
                        float* __restrict__ hg) {
    const int lane = threadIdx.x & 63;
    const int wid = (blockIdx.x * blockDim.x + threadIdx.x) >> 6;
    const int totalWaves = (gridDim.x * blockDim.x) >> 6;
    const int hlo = lane >> 4, hhi = 4 + (lane >> 4);
    const float4* asrc4 = (const float4*)asrc;
    for (int i = wid; i < NN; i += totalWaves) {
        const int r0 = rowptr[i], r1 = rowptr[i + 1];
        float ad[8], selfl[8];
        {
            float4 d0 = ((const float4*)adst)[2 * i], d1 = ((const float4*)adst)[2 * i + 1];
            ad[0] = d0.x; ad[1] = d0.y; ad[2] = d0.z; ad[3] = d0.w;
            ad[4] = d1.x; ad[5] = d1.y; ad[6] = d1.z; ad[7] = d1.w;
            float4 s0 = asrc4[2 * i], s1 = asrc4[2 * i + 1];
            float as[8] = {s0.x, s0.y, s0.z, s0.w, s1.x, s1.y, s1.z, s1.w};
#pragma unroll
            for (int hh = 0; hh < 8; ++hh) selfl[hh] = leaky02(as[hh] + ad[hh]);
        }
        // phase 1: segment max (self-loop included)
        float m[8];
#pragma unroll
        for (int hh = 0; hh < 8; ++hh) m[hh] = selfl[hh];
        for (int e = r0 + lane; e < r1; e += 64) {
            int j = colA[e];
            float4 s0 = asrc4[2 * j], s1 = asrc4[2 * j + 1];
            float as[8] = {s0.x, s0.y, s0.z, s0.w, s1.x, s1.y, s1.z, s1.w};
#pragma unroll
            for (int hh = 0; hh < 8; ++hh) m[hh] = fmaxf(m[hh], leaky02(as[hh] + ad[hh]));
        }
#pragma unroll
        for (int hh = 0; hh < 8; ++hh)
#pragma unroll
            for (int off = 32; off > 0; off >>= 1) m[hh] = fmaxf(m[hh], __shfl_xor(m[hh], off));
        // phase 1b: segment sum of exp
        float ss[8];
#pragma unroll
        for (int hh = 0; hh < 8; ++hh) ss[hh] = (lane == 0) ? __expf(selfl[hh] - m[hh]) : 0.f;
        for (int e = r0 + lane; e < r1; e += 64) {
            int j = colA[e];
            float4 s0 = asrc4[2 * j], s1 = asrc4[2 * j + 1];
            float as[8] = {s0.x, s0.y, s0.z, s0.w, s1.x, s1.y, s1.z, s1.w};
#pragma unroll
            for (int hh = 0; hh < 8; ++hh) ss[hh] += __expf(leaky02(as[hh] + ad[hh]) - m[hh]);
        }
#pragma unroll
        for (int hh = 0; hh < 8; ++hh)
#pragma unroll
            for (int off = 32; off > 0; off >>= 1) ss[hh] += __shfl_xor(ss[hh], off);
        const float rlo = 1.f / ss[hlo], rhi = 1.f / ss[hhi];
        const float mlo = m[hlo], mhi = m[hhi];
        const float adlo = ad[hlo], adhi = ad[hhi];
        // phase 2: weighted aggregation (self + neighbors), whole wave per edge
        float accLo, accHi;
        {
            float wlo = __expf(selfl[hlo] - mlo) * rlo;
            float whi = __expf(selfl[hhi] - mhi) * rhi;
            accLo = wlo * xg[(size_t)i * 128 + lane];
            accHi = whi * xg[(size_t)i * 128 + 64 + lane];
        }
        for (int e = r0; e < r1; ++e) {
            int j = colA[e];
            float wlo = __expf(leaky02(asrc[j * 8 + hlo] + adlo) - mlo) * rlo;
            float whi = __expf(leaky02(asrc[j * 8 + hhi] + adhi) - mhi) * rhi;
            accLo += wlo * xg[(size_t)j * 128 + lane];
            accHi += whi * xg[(size_t)j * 128 + 64 + lane];
        }
        float tsum = accLo + accHi;
        tsum += __shfl_xor(tsum, 16);
        tsum += __shfl_xor(tsum, 32);
        if (lane < 16) hg[i * 16 + lane] = tsum * 0.125f + bg[lane];
    }
}

// ---------------- pool + final ----------------

__global__ void pool_kernel(const float* __restrict__ hg, const int* __restrict__ batch,
                            float* __restrict__ pooled) {
    int idx = blockIdx.x * blockDim.x + threadIdx.x;
    if (idx < NN * 16) {
        int n = idx >> 4, c = idx & 15;
        atomicAdd(&pooled[batch[n] * 16 + c], hg[idx]);
    }
}

__global__ void final_kernel(const float* __restrict__ pooled, const float* __restrict__ Wf,
                             const float* __restrict__ bf, float* __restrict__ out) {
    int idx = blockIdx.x * blockDim.x + threadIdx.x;
    if (idx < GG * 3) {
        int g = idx / 3, j = idx - g * 3;
        float acc = bf[j];
#pragma unroll
        for (int c = 0; c < 16; ++c) acc += pooled[g * 16 + c] * Wf[c * 3 + j];
        out[idx] = acc;
    }
}

// ---------------- launcher ----------------

extern "C" void kernel_launch(void* const* d_in, const int* in_sizes, int n_in,
                              void* d_out, int out_size, void* d_ws, size_t ws_size,
                              hipStream_t stream) {
    const float* x = (const float*)d_in[0];
    const int* ei = (const int*)d_in[1];
    const int* batch = (const int*)d_in[2];
    const float* W1 = (const float*)d_in[3];  const float* b1 = (const float*)d_in[4];
    const float* g1 = (const float*)d_in[5];  const float* be1 = (const float*)d_in[6];
    const float* W2 = (const float*)d_in[7];  const float* b2 = (const float*)d_in[8];
    const float* g2 = (const float*)d_in[9];  const float* be2 = (const float*)d_in[10];
    const float* W3 = (const float*)d_in[11]; const float* b3 = (const float*)d_in[12];
    const float* g3 = (const float*)d_in[13]; const float* be3 = (const float*)d_in[14];
    const float* Wg = (const float*)d_in[15];
    const float* att_src = (const float*)d_in[16];
    const float* att_dst = (const float*)d_in[17];
    const float* bg = (const float*)d_in[18];
    const float* Wf = (const float*)d_in[19];
    const float* bf = (const float*)d_in[20];
    float* out = (float*)d_out;

    char* w = (char*)d_ws;
    auto alloc = [&](size_t bytes) -> char* {
        char* p = w;
        w += (bytes + 255) & ~(size_t)255;
        return p;
    };
    // --- zeroed region (one memset) ---
    int* fill = (int*)alloc((size_t)NN * 4);
    float* pooled = (float*)alloc((size_t)GG * 16 * 4);
    float* sums1 = (float*)alloc(64 * 4); float* ssq1 = (float*)alloc(64 * 4);
    float* sums2 = (float*)alloc(32 * 4); float* ssq2 = (float*)alloc(32 * 4);
    float* sums3 = (float*)alloc(16 * 4); float* ssq3 = (float*)alloc(16 * 4);
    size_t zeroBytes = (size_t)(w - (char*)d_ws);
    // --- rest ---
    float* a1 = (float*)alloc(64 * 4); float* bh1 = (float*)alloc(64 * 4);
    float* a2 = (float*)alloc(32 * 4); float* bh2 = (float*)alloc(32 * 4);
    float* a3 = (float*)alloc(16 * 4); float* bh3 = (float*)alloc(16 * 4);
    int* bsum = (int*)alloc(128 * 4);
    int* boff = (int*)alloc(128 * 4);
    int* rowptr = (int*)alloc((size_t)(NN + 1) * 4);
    int* colA = (int*)alloc((size_t)EE * 4);
    float* dinv = (float*)alloc((size_t)NN * 4);
    float* bufA = (float*)alloc((size_t)NN * 64 * 4);
    float* bufB = (float*)alloc((size_t)NN * 64 * 4);
    float* xg = (float*)alloc((size_t)NN * 128 * 4);
    // aliases into bufA (free after agg3):
    float* asrc = bufA;
    float* adst = bufA + (size_t)NN * 8;
    float* hg = bufA + (size_t)NN * 16;

    hipMemsetAsync(d_ws, 0, zeroBytes, stream);

    const int EB = (EE + 255) / 256;
    count_kernel<<<EB, 256, 0, stream>>>(ei, fill);
    scanA<<<NSCANBLK, SCAN_BLK, 0, stream>>>(fill, bsum);
    scanB<<<1, SCAN_BLK, 0, stream>>>(bsum, boff);
    scanC<<<NSCANBLK, SCAN_BLK, 0, stream>>>(fill, boff, rowptr, dinv);
    scatter_kernel<<<EB, 256, 0, stream>>>(ei, fill, colA);

    // layer 1: x[20] -> 64
    gemm_bn<20, 64, false><<<2048, 256, 0, stream>>>(x, nullptr, nullptr, W1, dinv, bufA);
    agg_kernel<64><<<2048, 256, 0, stream>>>(bufA, rowptr, colA, dinv, b1, bufB);
    bn_stats<64><<<512, 256, 0, stream>>>(bufB, sums1, ssq1);
    bn_finalize<64><<<1, 64, 0, stream>>>(sums1, ssq1, g1, be1, a1, bh1);

    // layer 2: 64 -> 32
    gemm_bn<64, 32, true><<<2048, 256, 0, stream>>>(bufB, a1, bh1, W2, dinv, bufA);
    agg_kernel<32><<<2048, 256, 0, stream>>>(bufA, rowptr, colA, dinv, b2, bufB);
    bn_stats<32><<<512, 256, 0, stream>>>(bufB, sums2, ssq2);
    bn_finalize<32><<<1, 64, 0, stream>>>(sums2, ssq2, g2, be2, a2, bh2);

    // layer 3: 32 -> 16
    gemm_bn<32, 16, true><<<2048, 256, 0, stream>>>(bufB, a2, bh2, W3, dinv, bufA);
    agg_kernel<16><<<2048, 256, 0, stream>>>(bufA, rowptr, colA, dinv, b3, bufB);
    bn_stats<16><<<512, 256, 0, stream>>>(bufB, sums3, ssq3);
    bn_finalize<16><<<1, 64, 0, stream>>>(sums3, ssq3, g3, be3, a3, bh3);

    // GAT
    gat_pre<<<2048, 256, 0, stream>>>(bufB, a3, bh3, Wg, att_src, att_dst, xg, asrc, adst);
    gat_agg<<<2048, 256, 0, stream>>>(xg, asrc, adst, rowptr, colA, bg, hg);

    // pool + classify
    pool_kernel<<<(NN * 16 + 255) / 256, 256, 0, stream>>>(hg, batch, pooled);
    final_kernel<<<(GG * 3 + 255) / 256, 256, 0, stream>>>(pooled, Wf, bf, out);
}

// Round 2
// 1213.458 us; speedup vs baseline: 1.4653x; 1.4653x over previous
//
#include <hip/hip_runtime.h>
#include <hip/hip_fp16.h>

constexpr int NN = 100000;   // nodes
constexpr int EE = 3200000;  // edges
constexpr int GG = 5000;     // graphs
constexpr float BNEPS = 1e-5f;

constexpr int SCAN_BLK = 256;
constexpr int SCAN_ITEMS = 1024;                       // 256 thr x 4
constexpr int NSCANBLK = (NN + SCAN_ITEMS - 1) / SCAN_ITEMS;  // 98

// ---------------- CSR build ----------------

__global__ void count_kernel(const int* __restrict__ ei, int* __restrict__ cnt) {
    int e = blockIdx.x * blockDim.x + threadIdx.x;
    if (e < EE) atomicAdd(&cnt[ei[EE + e]], 1);
}

__global__ void scanA(const int* __restrict__ cnt, int* __restrict__ bsum) {
    __shared__ int ls[SCAN_BLK];
    int t = threadIdx.x;
    int base = blockIdx.x * SCAN_ITEMS + t * 4;
    int s = 0;
#pragma unroll
    for (int k = 0; k < 4; ++k) { int i = base + k; if (i < NN) s += cnt[i]; }
    ls[t] = s; __syncthreads();
    for (int off = 128; off > 0; off >>= 1) {
        if (t < off) ls[t] += ls[t + off];
        __syncthreads();
    }
    if (t == 0) bsum[blockIdx.x] = ls[0];
}

__global__ void scanB(const int* __restrict__ bsum, int* __restrict__ boff) {
    __shared__ int ls[SCAN_BLK];
    int t = threadIdx.x;
    int v = (t < NSCANBLK) ? bsum[t] : 0;
    ls[t] = v; __syncthreads();
    for (int off = 1; off < SCAN_BLK; off <<= 1) {
        int x = 0;
        if (t >= off) x = ls[t - off];
        __syncthreads();
        ls[t] += x;
        __syncthreads();
    }
    if (t < NSCANBLK) boff[t] = ls[t] - v;  // exclusive
}

__global__ void scanC(int* __restrict__ cnt /* becomes fill-start */, const int* __restrict__ boff,
                      int* __restrict__ rowptr, float* __restrict__ dinv) {
    __shared__ int ls[SCAN_BLK];
    int t = threadIdx.x;
    int base = blockIdx.x * SCAN_ITEMS + t * 4;
    int c[4]; int s = 0;
#pragma unroll
    for (int k = 0; k < 4; ++k) { int i = base + k; c[k] = (i < NN) ? cnt[i] : 0; s += c[k]; }
    ls[t] = s; __syncthreads();
    for (int off = 1; off < SCAN_BLK; off <<= 1) {
        int x = 0;
        if (t >= off) x = ls[t - off];
        __syncthreads();
        ls[t] += x;
        __syncthreads();
    }
    int run = boff[blockIdx.x] + ls[t] - s;  // exclusive base for this thread
#pragma unroll
    for (int k = 0; k < 4; ++k) {
        int i = base + k;
        if (i < NN) {
            rowptr[i] = run;
            cnt[i] = run;  // fill cursor for scatter
            dinv[i] = rsqrtf((float)(c[k] + 1));  // +1 self-loop
            run += c[k];
            if (i == NN - 1) rowptr[NN] = run;
        }
    }
}

__global__ void scatter_kernel(const int* __restrict__ ei, int* __restrict__ fill,
                               int* __restrict__ colA) {
    int e = blockIdx.x * blockDim.x + threadIdx.x;
    if (e < EE) {
        int d = ei[EE + e];
        int pos = atomicAdd(&fill[d], 1);
        colA[pos] = ei[e];
    }
}

// ---------------- x pre-scale: xsc[n][k] = half(x[n][k] * dinv[n]), padded to 32 ch ----------------

__global__ void scale_x(const float* __restrict__ x, const float* __restrict__ dinv,
                        __half* __restrict__ xsc) {
    int idx = blockIdx.x * blockDim.x + threadIdx.x;
    if (idx < NN * 32) {
        int n = idx >> 5, k = idx & 31;
        float v = (k < 20) ? x[n * 20 + k] * dinv[n] : 0.f;
        xsc[idx] = __float2half(v);
    }
}

// ---------------- GEMM: optional BN-affine+ReLU on input; two epilogues ----------------
// SCALED=true : outH[node*FOUT+c] = half(acc * dinv[node])   (pre-aggregation form)
// SCALED=false: outF[node*FOUT+c] = acc + bias[c]            (post-aggregation form, layer 1)

template <int FIN, int FOUT, bool AFFINE, bool SCALED>
__global__ void gemm_k(const float* __restrict__ hin, const float* __restrict__ aArr,
                       const float* __restrict__ bArr, const float* __restrict__ W,
                       const float* __restrict__ dinv, const float* __restrict__ bias,
                       float* __restrict__ outF, __half* __restrict__ outH) {
    constexpr int NB = 256 / FOUT;  // nodes per group
    __shared__ float Wl[FIN * FOUT];
    __shared__ float rows[NB][FIN];
    const int t = threadIdx.x;
    for (int i = t; i < FIN * FOUT; i += 256) Wl[i] = W[i];
    const int c = t % FOUT, s = t / FOUT;
    const int ngrp = (NN + NB - 1) / NB;
    for (int grp = blockIdx.x; grp < ngrp; grp += gridDim.x) {
        __syncthreads();  // covers Wl on first iter; protects rows reuse after
        for (int i = t; i < NB * FIN; i += 256) {
            int sn = i / FIN, k = i % FIN;
            int n2 = grp * NB + sn;
            float v = 0.f;
            if (n2 < NN) {
                v = hin[(size_t)n2 * FIN + k];
                if constexpr (AFFINE) {
                    v = aArr[k] * v + bArr[k];
                    v = v > 0.f ? v : 0.f;
                }
            }
            rows[sn][k] = v;
        }
        __syncthreads();
        int node = grp * NB + s;
        if (node < NN) {
            float acc = 0.f;
#pragma unroll
            for (int k = 0; k < FIN; ++k) acc += rows[s][k] * Wl[k * FOUT + c];
            if constexpr (SCALED)
                outH[(size_t)node * FOUT + c] = __float2half(acc * dinv[node]);
            else
                outF[(size_t)node * FOUT + c] = acc + bias[c];
        }
    }
}

// ---------------- gather aggregation from fp16 source ----------------
// src rows are H2 half2 wide; out[i] = dinv[i]*(src[i] + sum_nbr src[j]) (+ bias), fp32,
// out row stride = OUTF floats (OUTF may be < 2*H2 for the padded-x case).

template <int H2, int OUTF>
__global__ void agg_half(const __half2* __restrict__ src, const int* __restrict__ rowptr,
                         const int* __restrict__ colA, const float* __restrict__ dinv,
                         const float* __restrict__ bias, float* __restrict__ out) {
    constexpr int SUB = 64 / H2;
    const int lane = threadIdx.x & 63;
    const int wid = (blockIdx.x * blockDim.x + threadIdx.x) >> 6;
    const int totalWaves = (gridDim.x * blockDim.x) >> 6;
    const int f = lane % H2;
    const int sub = lane / H2;
    const int stride = totalWaves * SUB;
    const bool valid = (2 * f) < OUTF;
    float bx = 0.f, by = 0.f;
    if (bias != nullptr && valid) {
        bx = bias[2 * f];
        by = (2 * f + 1 < OUTF) ? bias[2 * f + 1] : 0.f;
    }
    for (int i = wid * SUB + sub; i < NN; i += stride) {
        const int r0 = rowptr[i], r1 = rowptr[i + 1];
        float2 acc = __half22float2(src[(size_t)i * H2 + f]);  // self loop (pre-scaled by dinv[i])
        int e = r0;
        for (; e + 1 < r1; e += 2) {
            int j0 = colA[e], j1 = colA[e + 1];
            float2 v0 = __half22float2(src[(size_t)j0 * H2 + f]);
            float2 v1 = __half22float2(src[(size_t)j1 * H2 + f]);
            acc.x += v0.x + v1.x;
            acc.y += v0.y + v1.y;
        }
        if (e < r1) {
            float2 v = __half22float2(src[(size_t)colA[e] * H2 + f]);
            acc.x += v.x; acc.y += v.y;
        }
        const float d = dinv[i];
        if (valid) {
            out[(size_t)i * OUTF + 2 * f] = d * acc.x + bx;
            if (2 * f + 1 < OUTF) out[(size_t)i * OUTF + 2 * f + 1] = d * acc.y + by;
        }
    }
}

// ---------------- BN stats ----------------

template <int F>
__global__ void bn_stats(const float* __restrict__ h, float* __restrict__ sums,
                         float* __restrict__ ssq) {
    __shared__ float ls[F], lq[F];
    const int t = threadIdx.x;
    const int c = t % F;
    constexpr int ROWS = 256 / F;
    float s = 0.f, q = 0.f;
    for (int n = blockIdx.x * ROWS + t / F; n < NN; n += gridDim.x * ROWS) {
        float v = h[(size_t)n * F + c];
        s += v; q += v * v;
    }
    if (t < F) { ls[t] = 0.f; lq[t] = 0.f; }
    __syncthreads();
    atomicAdd(&ls[c], s);
    atomicAdd(&lq[c], q);
    __syncthreads();
    if (t < F) { atomicAdd(&sums[t], ls[t]); atomicAdd(&ssq[t], lq[t]); }
}

template <int F>
__global__ void bn_finalize(const float* __restrict__ sums, const float* __restrict__ ssq,
                            const float* __restrict__ g, const float* __restrict__ be,
                            float* __restrict__ aArr, float* __restrict__ bArr) {
    int c = threadIdx.x;
    if (c < F) {
        float mu = sums[c] / (float)NN;
        float var = ssq[c] / (float)NN - mu * mu;
        float a = g[c] * rsqrtf(var + BNEPS);
        aArr[c] = a;
        bArr[c] = be[c] - mu * a;
    }
}

// ---------------- GAT: xg = relu(bn(h3)) @ Wg (fp16) ; a_src/a_dst (fp32) ----------------

__global__ void gat_pre(const float* __restrict__ out3, const float* __restrict__ aArr,
                        const float* __restrict__ bArr, const float* __restrict__ Wg,
                        const float* __restrict__ att_src, const float* __restrict__ att_dst,
                        __half* __restrict__ xg, float* __restrict__ asrc,
                        float* __restrict__ adst) {
    __shared__ float Wl[16 * 128];
    __shared__ float row[2][16];
    __shared__ float red[2][128];
    const int t = threadIdx.x;
    for (int i = t; i < 16 * 128; i += 256) Wl[i] = Wg[i];
    const int c = t & 127, s = t >> 7;
    const float atts = att_src[c], attd = att_dst[c];
    const int h = c >> 4;
    const int cc = c & 15;
    const int ngrp = (NN + 1) / 2;
    for (int grp = blockIdx.x; grp < ngrp; grp += gridDim.x) {
        __syncthreads();
        if (t < 32) {
            int sn = t >> 4, k = t & 15;
            int n2 = grp * 2 + sn;
            float v = 0.f;
            if (n2 < NN) {
                v = out3[n2 * 16 + k];
                v = aArr[k] * v + bArr[k];
                v = v > 0.f ? v : 0.f;
            }
            row[sn][k] = v;
        }
        __syncthreads();
        float acc = 0.f;
#pragma unroll
        for (int k = 0; k < 16; ++k) acc += row[s][k] * Wl[k * 128 + c];
        int node = grp * 2 + s;
        if (node < NN) xg[(size_t)node * 128 + c] = __float2half(acc);
        red[s][c] = acc * atts;
        __syncthreads();
        if (cc == 0 && node < NN) {
            float v = 0.f;
#pragma unroll
            for (int k2 = 0; k2 < 16; ++k2) v += red[s][h * 16 + k2];
            asrc[node * 8 + h] = v;
        }
        __syncthreads();
        red[s][c] = acc * attd;
        __syncthreads();
        if (cc == 0 && node < NN) {
            float v = 0.f;
#pragma unroll
            for (int k2 = 0; k2 < 16; ++k2) v += red[s][h * 16 + k2];
            adst[node * 8 + h] = v;
        }
    }
}

// ---------------- GAT segment-softmax + aggregation, one wave per node, fp16 xg ----------------

__device__ __forceinline__ float leaky02(float x) { return x > 0.f ? x : 0.2f * x; }

__global__ void gat_agg2(const __half2* __restrict__ xg2, const float* __restrict__ asrc,
                         const float* __restrict__ adst, const int* __restrict__ rowptr,
                         const int* __restrict__ colA, const float* __restrict__ bg,
                         float* __restrict__ hg) {
    const int lane = threadIdx.x & 63;
    const int wid = (blockIdx.x * blockDim.x + threadIdx.x) >> 6;
    const int totalWaves = (gridDim.x * blockDim.x) >> 6;
    const int head = lane >> 3;  // lane holds channels 2*lane, 2*lane+1 -> head = 2*lane/16
    const float4* asrc4 = (const float4*)asrc;
    for (int i = wid; i < NN; i += totalWaves) {
        const int r0 = rowptr[i], r1 = rowptr[i + 1];
        float ad[8], selfl[8];
        {
            float4 d0 = ((const float4*)adst)[2 * i], d1 = ((const float4*)adst)[2 * i + 1];
            ad[0] = d0.x; ad[1] = d0.y; ad[2] = d0.z; ad[3] = d0.w;
            ad[4] = d1.x; ad[5] = d1.y; ad[6] = d1.z; ad[7] = d1.w;
            float4 s0 = asrc4[2 * i], s1 = asrc4[2 * i + 1];
            float as[8] = {s0.x, s0.y, s0.z, s0.w, s1.x, s1.y, s1.z, s1.w};
#pragma unroll
            for (int hh = 0; hh < 8; ++hh) selfl[hh] = leaky02(as[hh] + ad[hh]);
        }
        // phase 1: segment max (self-loop included)
        float m[8];
#pragma unroll
        for (int hh = 0; hh < 8; ++hh) m[hh] = selfl[hh];
        for (int e = r0 + lane; e < r1; e += 64) {
            int j = colA[e];
            float4 s0 = asrc4[2 * j], s1 = asrc4[2 * j + 1];
            float as[8] = {s0.x, s0.y, s0.z, s0.w, s1.x, s1.y, s1.z, s1.w};
#pragma unroll
            for (int hh = 0; hh < 8; ++hh) m[hh] = fmaxf(m[hh], leaky02(as[hh] + ad[hh]));
        }
#pragma unroll
        for (int hh = 0; hh < 8; ++hh)
#pragma unroll
            for (int off = 32; off > 0; off >>= 1) m[hh] = fmaxf(m[hh], __shfl_xor(m[hh], off));
        // phase 1b: segment sum of exp
        float ss[8];
#pragma unroll
        for (int hh = 0; hh < 8; ++hh) ss[hh] = (lane == 0) ? __expf(selfl[hh] - m[hh]) : 0.f;
        for (int e = r0 + lane; e < r1; e += 64) {
            int j = colA[e];
            float4 s0 = asrc4[2 * j], s1 = asrc4[2 * j + 1];
            float as[8] = {s0.x, s0.y, s0.z, s0.w, s1.x, s1.y, s1.z, s1.w};
#pragma unroll
            for (int hh = 0; hh < 8; ++hh) ss[hh] += __expf(leaky02(as[hh] + ad[hh]) - m[hh]);
        }
#pragma unroll
        for (int hh = 0; hh < 8; ++hh)
#pragma unroll
            for (int off = 32; off > 0; off >>= 1) ss[hh] += __shfl_xor(ss[hh], off);
        // per-lane head constants (8-way select tree, once per node)
        float mh = m[head];
        float rh = 1.f / ss[head];
        float adh = ad[head];
        float slh = selfl[head];
        // phase 2: weighted aggregation (self + neighbors), whole wave per edge, 2x unroll
        float2 acc;
        {
            float w = __expf(slh - mh) * rh;
            float2 v = __half22float2(xg2[(size_t)i * 64 + lane]);
            acc.x = w * v.x;
            acc.y = w * v.y;
        }
        int e = r0;
        for (; e + 1 < r1; e += 2) {
            int j0 = colA[e], j1 = colA[e + 1];
            float a0 = asrc[j0 * 8 + head];
            float a1 = asrc[j1 * 8 + head];
            float2 v0 = __half22float2(xg2[(size_t)j0 * 64 + lane]);
            float2 v1 = __half22float2(xg2[(size_t)j1 * 64 + lane]);
            float w0 = __expf(leaky02(a0 + adh) - mh) * rh;
            float w1 = __expf(leaky02(a1 + adh) - mh) * rh;
            acc.x += w0 * v0.x + w1 * v1.x;
            acc.y += w0 * v0.y + w1 * v1.y;
        }
        if (e < r1) {
            int j = colA[e];
            float w = __expf(leaky02(asrc[j * 8 + head] + adh) - mh) * rh;
            float2 v = __half22float2(xg2[(size_t)j * 64 + lane]);
            acc.x += w * v.x;
            acc.y += w * v.y;
        }
        // reduce over heads: lanes {l, l^8, l^16, l^32...} share channel pair (2*(l&7), +1)
#pragma unroll
        for (int off = 8; off < 64; off <<= 1) {
            acc.x += __shfl_xor(acc.x, off);
            acc.y += __shfl_xor(acc.y, off);
        }
        if (lane < 8) {
            hg[i * 16 + 2 * lane] = acc.x * 0.125f + bg[2 * lane];
            hg[i * 16 + 2 * lane + 1] = acc.y * 0.125f + bg[2 * lane + 1];
        }
    }
}

// ---------------- pool + final ----------------

__global__ void pool_kernel(const float* __restrict__ hg, const int* __restrict__ batch,
                            float* __restrict__ pooled) {
    int idx = blockIdx.x * blockDim.x + threadIdx.x;
    if (idx < NN * 16) {
        int n = idx >> 4, c = idx & 15;
        atomicAdd(&pooled[batch[n] * 16 + c], hg[idx]);
    }
}

__global__ void final_kernel(const float* __restrict__ pooled, const float* __restrict__ Wf,
                             const float* __restrict__ bf, float* __restrict__ out) {
    int idx = blockIdx.x * blockDim.x + threadIdx.x;
    if (idx < GG * 3) {
        int g = idx / 3, j = idx - g * 3;
        float acc = bf[j];
#pragma unroll
        for (int c = 0; c < 16; ++c) acc += pooled[g * 16 + c] * Wf[c * 3 + j];
        out[idx] = acc;
    }
}

// ---------------- launcher ----------------

extern "C" void kernel_launch(void* const* d_in, const int* in_sizes, int n_in,
                              void* d_out, int out_size, void* d_ws, size_t ws_size,
                              hipStream_t stream) {
    const float* x = (const float*)d_in[0];
    const int* ei = (const int*)d_in[1];
    const int* batch = (const int*)d_in[2];
    const float* W1 = (const float*)d_in[3];  const float* b1 = (const float*)d_in[4];
    const float* g1 = (const float*)d_in[5];  const float* be1 = (const float*)d_in[6];
    const float* W2 = (const float*)d_in[7];  const float* b2 = (const float*)d_in[8];
    const float* g2 = (const float*)d_in[9];  const float* be2 = (const float*)d_in[10];
    const float* W3 = (const float*)d_in[11]; const float* b3 = (const float*)d_in[12];
    const float* g3 = (const float*)d_in[13]; const float* be3 = (const float*)d_in[14];
    const float* Wg = (const float*)d_in[15];
    const float* att_src = (const float*)d_in[16];
    const float* att_dst = (const float*)d_in[17];
    const float* bg = (const float*)d_in[18];
    const float* Wf = (const float*)d_in[19];
    const float* bf = (const float*)d_in[20];
    float* out = (float*)d_out;

    char* w = (char*)d_ws;
    auto alloc = [&](size_t bytes) -> char* {
        char* p = w;
        w += (bytes + 255) & ~(size_t)255;
        return p;
    };
    // --- zeroed region (one memset) ---
    int* fill = (int*)alloc((size_t)NN * 4);
    float* pooled = (float*)alloc((size_t)GG * 16 * 4);
    float* sums1 = (float*)alloc(64 * 4); float* ssq1 = (float*)alloc(64 * 4);
    float* sums2 = (float*)alloc(32 * 4); float* ssq2 = (float*)alloc(32 * 4);
    float* sums3 = (float*)alloc(16 * 4); float* ssq3 = (float*)alloc(16 * 4);
    size_t zeroBytes = (size_t)(w - (char*)d_ws);
    // --- rest ---
    float* a1 = (float*)alloc(64 * 4); float* bh1 = (float*)alloc(64 * 4);
    float* a2 = (float*)alloc(32 * 4); float* bh2 = (float*)alloc(32 * 4);
    float* a3 = (float*)alloc(16 * 4); float* bh3 = (float*)alloc(16 * 4);
    int* bsum = (int*)alloc(128 * 4);
    int* boff = (int*)alloc(128 * 4);
    int* rowptr = (int*)alloc((size_t)(NN + 1) * 4);
    int* colA = (int*)alloc((size_t)EE * 4);
    float* dinv = (float*)alloc((size_t)NN * 4);
    char* A = alloc((size_t)NN * 64 * 4);  // 25.6 MB scratch block A
    char* B = alloc((size_t)NN * 64 * 4);  // 25.6 MB scratch block B

    // lifetime-based aliases
    __half* xsc  = (__half*)B;                               // [NN,32] fp16   6.4 MB
    float*  aggx = (float*)(B + (size_t)NN * 32 * 2);        // [NN,20] fp32   8.0 MB
    float*  h1   = (float*)A;                                // [NN,64] fp32  25.6 MB
    __half* hs2  = (__half*)B;                               // [NN,32] fp16   6.4 MB
    float*  h2   = (float*)(B + (size_t)NN * 32 * 2);        // [NN,32] fp32  12.8 MB
    __half* hs3  = (__half*)A;                               // [NN,16] fp16   3.2 MB
    float*  h3   = (float*)(A + (size_t)NN * 16 * 2);        // [NN,16] fp32   6.4 MB
    __half* xgh  = (__half*)B;                               // [NN,128] fp16 25.6 MB
    float*  asrc = (float*)(A + (size_t)NN * 24 * 4);        // [NN,8]  fp32   3.2 MB
    float*  adst = (float*)(A + (size_t)NN * 32 * 4);        // [NN,8]  fp32   3.2 MB
    float*  hg   = (float*)(A + (size_t)NN * 40 * 4);        // [NN,16] fp32   6.4 MB

    hipMemsetAsync(d_ws, 0, zeroBytes, stream);

    const int EB = (EE + 255) / 256;
    count_kernel<<<EB, 256, 0, stream>>>(ei, fill);
    scanA<<<NSCANBLK, SCAN_BLK, 0, stream>>>(fill, bsum);
    scanB<<<1, SCAN_BLK, 0, stream>>>(bsum, boff);
    scanC<<<NSCANBLK, SCAN_BLK, 0, stream>>>(fill, boff, rowptr, dinv);
    scatter_kernel<<<EB, 256, 0, stream>>>(ei, fill, colA);

    // layer 1: aggregate x first (20ch padded to 32 fp16), then GEMM 20->64 (+b1)
    scale_x<<<(NN * 32 + 255) / 256, 256, 0, stream>>>(x, dinv, xsc);
    agg_half<16, 20><<<2048, 256, 0, stream>>>((const __half2*)xsc, rowptr, colA, dinv, nullptr, aggx);
    gemm_k<20, 64, false, false><<<2048, 256, 0, stream>>>(aggx, nullptr, nullptr, W1, dinv, b1, h1, nullptr);
    bn_stats<64><<<512, 256, 0, stream>>>(h1, sums1, ssq1);
    bn_finalize<64><<<1, 64, 0, stream>>>(sums1, ssq1, g1, be1, a1, bh1);

    // layer 2: 64 -> 32 (fp16 pre-agg buffer)
    gemm_k<64, 32, true, true><<<2048, 256, 0, stream>>>(h1, a1, bh1, W2, dinv, nullptr, nullptr, hs2);
    agg_half<16, 32><<<2048, 256, 0, stream>>>((const __half2*)hs2, rowptr, colA, dinv, b2, h2);
    bn_stats<32><<<512, 256, 0, stream>>>(h2, sums2, ssq2);
    bn_finalize<32><<<1, 64, 0, stream>>>(sums2, ssq2, g2, be2, a2, bh2);

    // layer 3: 32 -> 16 (fp16 pre-agg buffer)
    gemm_k<32, 16, true, true><<<2048, 256, 0, stream>>>(h2, a2, bh2, W3, dinv, nullptr, nullptr, hs3);
    agg_half<8, 16><<<2048, 256, 0, stream>>>((const __half2*)hs3, rowptr, colA, dinv, b3, h3);
    bn_stats<16><<<512, 256, 0, stream>>>(h3, sums3, ssq3);
    bn_finalize<16><<<1, 64, 0, stream>>>(sums3, ssq3, g3, be3, a3, bh3);

    // GAT (fp16 xg)
    gat_pre<<<2048, 256, 0, stream>>>(h3, a3, bh3, Wg, att_src, att_dst, xgh, asrc, adst);
    gat_agg2<<<2048, 256, 0, stream>>>((const __half2*)xgh, asrc, adst, rowptr, colA, bg, hg);

    // pool + classify
    pool_kernel<<<(NN * 16 + 255) / 256, 256, 0, stream>>>(hg, batch, pooled);
    final_kernel<<<(GG * 3 + 255) / 256, 256, 0, stream>>>(pooled, Wf, bf, out);
}

// Round 3
// 969.827 us; speedup vs baseline: 1.8334x; 1.2512x over previous
//
#include <hip/hip_runtime.h>
#include <hip/hip_fp16.h>

constexpr int NN = 100000;   // nodes
constexpr int EE = 3200000;  // edges
constexpr int GG = 5000;     // graphs
constexpr float BNEPS = 1e-5f;

constexpr int SCAN_BLK = 256;
constexpr int SCAN_ITEMS = 1024;                       // 256 thr x 4
constexpr int NSCANBLK = (NN + SCAN_ITEMS - 1) / SCAN_ITEMS;  // 98

// ---------------- CSR build ----------------

__global__ void count_kernel(const int* __restrict__ ei, int* __restrict__ cnt) {
    int e = blockIdx.x * blockDim.x + threadIdx.x;
    if (e < EE) atomicAdd(&cnt[ei[EE + e]], 1);
}

__global__ void scanA(const int* __restrict__ cnt, int* __restrict__ bsum) {
    __shared__ int ls[SCAN_BLK];
    int t = threadIdx.x;
    int base = blockIdx.x * SCAN_ITEMS + t * 4;
    int s = 0;
#pragma unroll
    for (int k = 0; k < 4; ++k) { int i = base + k; if (i < NN) s += cnt[i]; }
    ls[t] = s; __syncthreads();
    for (int off = 128; off > 0; off >>= 1) {
        if (t < off) ls[t] += ls[t + off];
        __syncthreads();
    }
    if (t == 0) bsum[blockIdx.x] = ls[0];
}

__global__ void scanB(const int* __restrict__ bsum, int* __restrict__ boff) {
    __shared__ int ls[SCAN_BLK];
    int t = threadIdx.x;
    int v = (t < NSCANBLK) ? bsum[t] : 0;
    ls[t] = v; __syncthreads();
    for (int off = 1; off < SCAN_BLK; off <<= 1) {
        int x = 0;
        if (t >= off) x = ls[t - off];
        __syncthreads();
        ls[t] += x;
        __syncthreads();
    }
    if (t < NSCANBLK) boff[t] = ls[t] - v;  // exclusive
}

__global__ void scanC(int* __restrict__ cnt /* becomes fill-start */, const int* __restrict__ boff,
                      int* __restrict__ rowptr, float* __restrict__ dinv) {
    __shared__ int ls[SCAN_BLK];
    int t = threadIdx.x;
    int base = blockIdx.x * SCAN_ITEMS + t * 4;
    int c[4]; int s = 0;
#pragma unroll
    for (int k = 0; k < 4; ++k) { int i = base + k; c[k] = (i < NN) ? cnt[i] : 0; s += c[k]; }
    ls[t] = s; __syncthreads();
    for (int off = 1; off < SCAN_BLK; off <<= 1) {
        int x = 0;
        if (t >= off) x = ls[t - off];
        __syncthreads();
        ls[t] += x;
        __syncthreads();
    }
    int run = boff[blockIdx.x] + ls[t] - s;  // exclusive base for this thread
#pragma unroll
    for (int k = 0; k < 4; ++k) {
        int i = base + k;
        if (i < NN) {
            rowptr[i] = run;
            cnt[i] = run;  // fill cursor for scatter
            dinv[i] = rsqrtf((float)(c[k] + 1));  // +1 self-loop
            run += c[k];
            if (i == NN - 1) rowptr[NN] = run;
        }
    }
}

__global__ void scatter_kernel(const int* __restrict__ ei, int* __restrict__ fill,
                               int* __restrict__ colA) {
    int e = blockIdx.x * blockDim.x + threadIdx.x;
    if (e < EE) {
        int d = ei[EE + e];
        int pos = atomicAdd(&fill[d], 1);
        colA[pos] = ei[e];
    }
}

// ---------------- x pre-scale: xsc[n][k] = half(x[n][k] * dinv[n]), 20 ch tight ----------------

__global__ void scale_x(const float* __restrict__ x, const float* __restrict__ dinv,
                        __half* __restrict__ xsc) {
    int idx = blockIdx.x * blockDim.x + threadIdx.x;
    if (idx < NN * 20) {
        int n = idx / 20, k = idx - n * 20;
        xsc[idx] = __float2half(x[idx] * dinv[n]);
        (void)k;
    }
}

// ---------------- GEMM: optional BN-affine+ReLU on input; two epilogues ----------------
// SCALED=true : outH[node*FOUT+c] = half(acc * dinv[node])   (pre-aggregation form)
// SCALED=false: outF[node*FOUT+c] = acc + bias[c]            (post-aggregation form, layer 1)

template <int FIN, int FOUT, bool AFFINE, bool SCALED>
__global__ void gemm_k(const float* __restrict__ hin, const float* __restrict__ aArr,
                       const float* __restrict__ bArr, const float* __restrict__ W,
                       const float* __restrict__ dinv, const float* __restrict__ bias,
                       float* __restrict__ outF, __half* __restrict__ outH) {
    constexpr int NB = 256 / FOUT;  // nodes per group
    __shared__ float Wl[FIN * FOUT];
    __shared__ float rows[NB][FIN];
    const int t = threadIdx.x;
    for (int i = t; i < FIN * FOUT; i += 256) Wl[i] = W[i];
    const int c = t % FOUT, s = t / FOUT;
    const int ngrp = (NN + NB - 1) / NB;
    for (int grp = blockIdx.x; grp < ngrp; grp += gridDim.x) {
        __syncthreads();  // covers Wl on first iter; protects rows reuse after
        for (int i = t; i < NB * FIN; i += 256) {
            int sn = i / FIN, k = i % FIN;
            int n2 = grp * NB + sn;
            float v = 0.f;
            if (n2 < NN) {
                v = hin[(size_t)n2 * FIN + k];
                if constexpr (AFFINE) {
                    v = aArr[k] * v + bArr[k];
                    v = v > 0.f ? v : 0.f;
                }
            }
            rows[sn][k] = v;
        }
        __syncthreads();
        int node = grp * NB + s;
        if (node < NN) {
            float acc = 0.f;
#pragma unroll
            for (int k = 0; k < FIN; ++k) acc += rows[s][k] * Wl[k * FOUT + c];
            if constexpr (SCALED)
                outH[(size_t)node * FOUT + c] = __float2half(acc * dinv[node]);
            else
                outF[(size_t)node * FOUT + c] = acc + bias[c];
        }
    }
}

// ---------------- gather aggregation from fp16 source ----------------
// src rows are H2 half2 wide; out[i] = dinv[i]*(src[i] + sum_nbr src[j]) (+ bias), fp32,
// out row stride = OUTF floats. H2 need not divide 64 (tail lanes idle).

template <int H2, int OUTF>
__global__ void agg_half(const __half2* __restrict__ src, const int* __restrict__ rowptr,
                         const int* __restrict__ colA, const float* __restrict__ dinv,
                         const float* __restrict__ bias, float* __restrict__ out) {
    constexpr int SUB = 64 / H2;
    const int lane = threadIdx.x & 63;
    const int wid = (blockIdx.x * blockDim.x + threadIdx.x) >> 6;
    const int totalWaves = (gridDim.x * blockDim.x) >> 6;
    const int f = lane % H2;
    const int sub = lane / H2;
    const int stride = totalWaves * SUB;
    float bx = 0.f, by = 0.f;
    if (bias != nullptr) {
        bx = bias[2 * f];
        by = (2 * f + 1 < OUTF) ? bias[2 * f + 1] : 0.f;
    }
    const int i0 = (sub < SUB) ? wid * SUB + sub : NN;  // idle tail lanes skip
    for (int i = i0; i < NN; i += stride) {
        const int r0 = rowptr[i], r1 = rowptr[i + 1];
        float2 acc = __half22float2(src[(size_t)i * H2 + f]);  // self loop (pre-scaled by dinv[i])
        float2 acc2 = {0.f, 0.f};
        int e = r0;
        for (; e + 3 < r1; e += 4) {
            int j0 = colA[e], j1 = colA[e + 1], j2 = colA[e + 2], j3 = colA[e + 3];
            float2 v0 = __half22float2(src[(size_t)j0 * H2 + f]);
            float2 v1 = __half22float2(src[(size_t)j1 * H2 + f]);
            float2 v2 = __half22float2(src[(size_t)j2 * H2 + f]);
            float2 v3 = __half22float2(src[(size_t)j3 * H2 + f]);
            acc.x += v0.x + v1.x;
            acc.y += v0.y + v1.y;
            acc2.x += v2.x + v3.x;
            acc2.y += v2.y + v3.y;
        }
        for (; e < r1; ++e) {
            float2 v = __half22float2(src[(size_t)colA[e] * H2 + f]);
            acc.x += v.x; acc.y += v.y;
        }
        acc.x += acc2.x; acc.y += acc2.y;
        const float d = dinv[i];
        out[(size_t)i * OUTF + 2 * f] = d * acc.x + bx;
        if (2 * f + 1 < OUTF) out[(size_t)i * OUTF + 2 * f + 1] = d * acc.y + by;
    }
}

// ---------------- BN stats ----------------

template <int F>
__global__ void bn_stats(const float* __restrict__ h, float* __restrict__ sums,
                         float* __restrict__ ssq) {
    __shared__ float ls[F], lq[F];
    const int t = threadIdx.x;
    const int c = t % F;
    constexpr int ROWS = 256 / F;
    float s = 0.f, q = 0.f;
    for (int n = blockIdx.x * ROWS + t / F; n < NN; n += gridDim.x * ROWS) {
        float v = h[(size_t)n * F + c];
        s += v; q += v * v;
    }
    if (t < F) { ls[t] = 0.f; lq[t] = 0.f; }
    __syncthreads();
    atomicAdd(&ls[c], s);
    atomicAdd(&lq[c], q);
    __syncthreads();
    if (t < F) { atomicAdd(&sums[t], ls[t]); atomicAdd(&ssq[t], lq[t]); }
}

template <int F>
__global__ void bn_finalize(const float* __restrict__ sums, const float* __restrict__ ssq,
                            const float* __restrict__ g, const float* __restrict__ be,
                            float* __restrict__ aArr, float* __restrict__ bArr) {
    int c = threadIdx.x;
    if (c < F) {
        float mu = sums[c] / (float)NN;
        float var = ssq[c] / (float)NN - mu * mu;
        float a = g[c] * rsqrtf(var + BNEPS);
        aArr[c] = a;
        bArr[c] = be[c] - mu * a;
    }
}

// ---------------- GAT: xg = relu(bn(h3)) @ Wg (fp16) ; a_src/a_dst (fp32) ----------------

__global__ void gat_pre(const float* __restrict__ out3, const float* __restrict__ aArr,
                        const float* __restrict__ bArr, const float* __restrict__ Wg,
                        const float* __restrict__ att_src, const float* __restrict__ att_dst,
                        __half* __restrict__ xg, float* __restrict__ asrc,
                        float* __restrict__ adst) {
    __shared__ float Wl[16 * 128];
    __shared__ float row[2][16];
    __shared__ float red[2][128];
    const int t = threadIdx.x;
    for (int i = t; i < 16 * 128; i += 256) Wl[i] = Wg[i];
    const int c = t & 127, s = t >> 7;
    const float atts = att_src[c], attd = att_dst[c];
    const int h = c >> 4;
    const int cc = c & 15;
    const int ngrp = (NN + 1) / 2;
    for (int grp = blockIdx.x; grp < ngrp; grp += gridDim.x) {
        __syncthreads();
        if (t < 32) {
            int sn = t >> 4, k = t & 15;
            int n2 = grp * 2 + sn;
            float v = 0.f;
            if (n2 < NN) {
                v = out3[n2 * 16 + k];
                v = aArr[k] * v + bArr[k];
                v = v > 0.f ? v : 0.f;
            }
            row[sn][k] = v;
        }
        __syncthreads();
        float acc = 0.f;
#pragma unroll
        for (int k = 0; k < 16; ++k) acc += row[s][k] * Wl[k * 128 + c];
        int node = grp * 2 + s;
        if (node < NN) xg[(size_t)node * 128 + c] = __float2half(acc);
        red[s][c] = acc * atts;
        __syncthreads();
        if (cc == 0 && node < NN) {
            float v = 0.f;
#pragma unroll
            for (int k2 = 0; k2 < 16; ++k2) v += red[s][h * 16 + k2];
            asrc[node * 8 + h] = v;
        }
        __syncthreads();
        red[s][c] = acc * attd;
        __syncthreads();
        if (cc == 0 && node < NN) {
            float v = 0.f;
#pragma unroll
            for (int k2 = 0; k2 < 16; ++k2) v += red[s][h * 16 + k2];
            adst[node * 8 + h] = v;
        }
    }
}

// ---------------- GAT single-pass: unnormalized accumulate, divide at end ----------------
// alpha_j = exp(l_j)/sum exp  ==  (no max subtraction needed; logits O(few))

__device__ __forceinline__ float leaky02(float x) { return x > 0.f ? x : 0.2f * x; }

__global__ void gat_agg3(const __half2* __restrict__ xg2, const float* __restrict__ asrc,
                         const float* __restrict__ adst, const int* __restrict__ rowptr,
                         const int* __restrict__ colA, const float* __restrict__ bg,
                         float* __restrict__ hg) {
    const int lane = threadIdx.x & 63;
    const int wid = (blockIdx.x * blockDim.x + threadIdx.x) >> 6;
    const int totalWaves = (gridDim.x * blockDim.x) >> 6;
    const int head = lane >> 3;  // lane holds channel pair `lane`; head = lane/8
    for (int i = wid; i < NN; i += totalWaves) {
        const int r0 = rowptr[i], r1 = rowptr[i + 1];
        const float adh = adst[i * 8 + head];
        // self-loop
        float ssum;
        float2 acc, acc2 = {0.f, 0.f};
        {
            float w = __expf(leaky02(asrc[i * 8 + head] + adh));
            float2 v = __half22float2(xg2[(size_t)i * 64 + lane]);
            acc.x = w * v.x;
            acc.y = w * v.y;
            ssum = w;
        }
        int e = r0;
        for (; e + 3 < r1; e += 4) {
            int j0 = colA[e], j1 = colA[e + 1], j2 = colA[e + 2], j3 = colA[e + 3];
            float a0 = asrc[j0 * 8 + head];
            float a1 = asrc[j1 * 8 + head];
            float a2 = asrc[j2 * 8 + head];
            float a3 = asrc[j3 * 8 + head];
            float2 v0 = __half22float2(xg2[(size_t)j0 * 64 + lane]);
            float2 v1 = __half22float2(xg2[(size_t)j1 * 64 + lane]);
            float2 v2 = __half22float2(xg2[(size_t)j2 * 64 + lane]);
            float2 v3 = __half22float2(xg2[(size_t)j3 * 64 + lane]);
            float w0 = __expf(leaky02(a0 + adh));
            float w1 = __expf(leaky02(a1 + adh));
            float w2 = __expf(leaky02(a2 + adh));
            float w3 = __expf(leaky02(a3 + adh));
            acc.x += w0 * v0.x + w1 * v1.x;
            acc.y += w0 * v0.y + w1 * v1.y;
            acc2.x += w2 * v2.x + w3 * v3.x;
            acc2.y += w2 * v2.y + w3 * v3.y;
            ssum += (w0 + w1) + (w2 + w3);
        }
        for (; e < r1; ++e) {
            int j = colA[e];
            float w = __expf(leaky02(asrc[j * 8 + head] + adh));
            float2 v = __half22float2(xg2[(size_t)j * 64 + lane]);
            acc.x += w * v.x;
            acc.y += w * v.y;
            ssum += w;
        }
        const float inv = 1.f / ssum;
        acc.x = (acc.x + acc2.x) * inv;
        acc.y = (acc.y + acc2.y) * inv;
        // reduce over heads: lanes {l, l^8, l^16, l^32} share channel pair (lane&7)
#pragma unroll
        for (int off = 8; off < 64; off <<= 1) {
            acc.x += __shfl_xor(acc.x, off);
            acc.y += __shfl_xor(acc.y, off);
        }
        if (lane < 8) {
            hg[i * 16 + 2 * lane] = acc.x * 0.125f + bg[2 * lane];
            hg[i * 16 + 2 * lane + 1] = acc.y * 0.125f + bg[2 * lane + 1];
        }
    }
}

// ---------------- pool + final ----------------

__global__ void pool_kernel(const float* __restrict__ hg, const int* __restrict__ batch,
                            float* __restrict__ pooled) {
    int idx = blockIdx.x * blockDim.x + threadIdx.x;
    if (idx < NN * 16) {
        int n = idx >> 4, c = idx & 15;
        atomicAdd(&pooled[batch[n] * 16 + c], hg[idx]);
    }
}

__global__ void final_kernel(const float* __restrict__ pooled, const float* __restrict__ Wf,
                             const float* __restrict__ bf, float* __restrict__ out) {
    int idx = blockIdx.x * blockDim.x + threadIdx.x;
    if (idx < GG * 3) {
        int g = idx / 3, j = idx - g * 3;
        float acc = bf[j];
#pragma unroll
        for (int c = 0; c < 16; ++c) acc += pooled[g * 16 + c] * Wf[c * 3 + j];
        out[idx] = acc;
    }
}

// ---------------- launcher ----------------

extern "C" void kernel_launch(void* const* d_in, const int* in_sizes, int n_in,
                              void* d_out, int out_size, void* d_ws, size_t ws_size,
                              hipStream_t stream) {
    const float* x = (const float*)d_in[0];
    const int* ei = (const int*)d_in[1];
    const int* batch = (const int*)d_in[2];
    const float* W1 = (const float*)d_in[3];  const float* b1 = (const float*)d_in[4];
    const float* g1 = (const float*)d_in[5];  const float* be1 = (const float*)d_in[6];
    const float* W2 = (const float*)d_in[7];  const float* b2 = (const float*)d_in[8];
    const float* g2 = (const float*)d_in[9];  const float* be2 = (const float*)d_in[10];
    const float* W3 = (const float*)d_in[11]; const float* b3 = (const float*)d_in[12];
    const float* g3 = (const float*)d_in[13]; const float* be3 = (const float*)d_in[14];
    const float* Wg = (const float*)d_in[15];
    const float* att_src = (const float*)d_in[16];
    const float* att_dst = (const float*)d_in[17];
    const float* bg = (const float*)d_in[18];
    const float* Wf = (const float*)d_in[19];
    const float* bf = (const float*)d_in[20];
    float* out = (float*)d_out;

    char* w = (char*)d_ws;
    auto alloc = [&](size_t bytes) -> char* {
        char* p = w;
        w += (bytes + 255) & ~(size_t)255;
        return p;
    };
    // --- zeroed region (one memset) ---
    int* fill = (int*)alloc((size_t)NN * 4);
    float* pooled = (float*)alloc((size_t)GG * 16 * 4);
    float* sums1 = (float*)alloc(64 * 4); float* ssq1 = (float*)alloc(64 * 4);
    float* sums2 = (float*)alloc(32 * 4); float* ssq2 = (float*)alloc(32 * 4);
    float* sums3 = (float*)alloc(16 * 4); float* ssq3 = (float*)alloc(16 * 4);
    size_t zeroBytes = (size_t)(w - (char*)d_ws);
    // --- rest ---
    float* a1 = (float*)alloc(64 * 4); float* bh1 = (float*)alloc(64 * 4);
    float* a2 = (float*)alloc(32 * 4); float* bh2 = (float*)alloc(32 * 4);
    float* a3 = (float*)alloc(16 * 4); float* bh3 = (float*)alloc(16 * 4);
    int* bsum = (int*)alloc(128 * 4);
    int* boff = (int*)alloc(128 * 4);
    int* rowptr = (int*)alloc((size_t)(NN + 1) * 4);
    int* colA = (int*)alloc((size_t)EE * 4);
    float* dinv = (float*)alloc((size_t)NN * 4);
    char* A = alloc((size_t)NN * 64 * 4);  // 25.6 MB scratch block A
    char* B = alloc((size_t)NN * 64 * 4);  // 25.6 MB scratch block B

    // lifetime-based aliases
    __half* xsc  = (__half*)B;                               // [NN,20] fp16   4.0 MB
    float*  aggx = (float*)(B + (size_t)NN * 32 * 2);        // [NN,20] fp32   8.0 MB
    float*  h1   = (float*)A;                                // [NN,64] fp32  25.6 MB
    __half* hs2  = (__half*)B;                               // [NN,32] fp16   6.4 MB
    float*  h2   = (float*)(B + (size_t)NN * 32 * 2);        // [NN,32] fp32  12.8 MB
    __half* hs3  = (__half*)A;                               // [NN,16] fp16   3.2 MB
    float*  h3   = (float*)(A + (size_t)NN * 16 * 2);        // [NN,16] fp32   6.4 MB
    __half* xgh  = (__half*)B;                               // [NN,128] fp16 25.6 MB
    float*  asrc = (float*)(A + (size_t)NN * 24 * 4);        // [NN,8]  fp32   3.2 MB
    float*  adst = (float*)(A + (size_t)NN * 32 * 4);        // [NN,8]  fp32   3.2 MB
    float*  hg   = (float*)(A + (size_t)NN * 40 * 4);        // [NN,16] fp32   6.4 MB

    hipMemsetAsync(d_ws, 0, zeroBytes, stream);

    const int EB = (EE + 255) / 256;
    count_kernel<<<EB, 256, 0, stream>>>(ei, fill);
    scanA<<<NSCANBLK, SCAN_BLK, 0, stream>>>(fill, bsum);
    scanB<<<1, SCAN_BLK, 0, stream>>>(bsum, boff);
    scanC<<<NSCANBLK, SCAN_BLK, 0, stream>>>(fill, boff, rowptr, dinv);
    scatter_kernel<<<EB, 256, 0, stream>>>(ei, fill, colA);

    // layer 1: aggregate x first (20ch tight fp16), then GEMM 20->64 (+b1)
    scale_x<<<(NN * 20 + 255) / 256, 256, 0, stream>>>(x, dinv, xsc);
    agg_half<10, 20><<<2048, 256, 0, stream>>>((const __half2*)xsc, rowptr, colA, dinv, nullptr, aggx);
    gemm_k<20, 64, false, false><<<2048, 256, 0, stream>>>(aggx, nullptr, nullptr, W1, dinv, b1, h1, nullptr);
    bn_stats<64><<<512, 256, 0, stream>>>(h1, sums1, ssq1);
    bn_finalize<64><<<1, 64, 0, stream>>>(sums1, ssq1, g1, be1, a1, bh1);

    // layer 2: 64 -> 32 (fp16 pre-agg buffer)
    gemm_k<64, 32, true, true><<<2048, 256, 0, stream>>>(h1, a1, bh1, W2, dinv, nullptr, nullptr, hs2);
    agg_half<16, 32><<<2048, 256, 0, stream>>>((const __half2*)hs2, rowptr, colA, dinv, b2, h2);
    bn_stats<32><<<512, 256, 0, stream>>>(h2, sums2, ssq2);
    bn_finalize<32><<<1, 64, 0, stream>>>(sums2, ssq2, g2, be2, a2, bh2);

    // layer 3: 32 -> 16 (fp16 pre-agg buffer)
    gemm_k<32, 16, true, true><<<2048, 256, 0, stream>>>(h2, a2, bh2, W3, dinv, nullptr, nullptr, hs3);
    agg_half<8, 16><<<2048, 256, 0, stream>>>((const __half2*)hs3, rowptr, colA, dinv, b3, h3);
    bn_stats<16><<<512, 256, 0, stream>>>(h3, sums3, ssq3);
    bn_finalize<16><<<1, 64, 0, stream>>>(sums3, ssq3, g3, be3, a3, bh3);

    // GAT (fp16 xg), single-pass softmax+aggregate
    gat_pre<<<2048, 256, 0, stream>>>(h3, a3, bh3, Wg, att_src, att_dst, xgh, asrc, adst);
    gat_agg3<<<2048, 256, 0, stream>>>((const __half2*)xgh, asrc, adst, rowptr, colA, bg, hg);

    // pool + classify
    pool_kernel<<<(NN * 16 + 255) / 256, 256, 0, stream>>>(hg, batch, pooled);
    final_kernel<<<(GG * 3 + 255) / 256, 256, 0, stream>>>(pooled, Wf, bf, out);
}

// Round 4
// 837.611 us; speedup vs baseline: 2.1228x; 1.1578x over previous
//
#include <hip/hip_runtime.h>
#include <hip/hip_fp16.h>

constexpr int NN = 100000;   // nodes
constexpr int EE = 3200000;  // edges
constexpr int GG = 5000;     // graphs
constexpr float BNEPS = 1e-5f;

constexpr int XCDS = 8;
constexpr int NODES_PER_XCD = (NN + XCDS - 1) / XCDS;  // 12500

constexpr int SCAN_BLK = 256;
constexpr int SCAN_ITEMS = 1024;                       // 256 thr x 4
constexpr int NSCANBLK = (NN + SCAN_ITEMS - 1) / SCAN_ITEMS;  // 98

// ---------------- CSR build (XCD-partitioned by dst range) ----------------
// blockIdx%8 ~ XCD (round-robin dispatch heuristic). Each XCD-group owns dst range
// [r*12500, (r+1)*12500): its cnt/fill/colA lines stay in that XCD's L2 ->
// write-combining instead of cross-XCD line ping-pong (R3: 195MB writeback for 12.8MB data).

__global__ void count_x(const int* __restrict__ ei, int* __restrict__ cnt) {
    const int r = blockIdx.x & 7;
    const int bi = blockIdx.x >> 3;
    const int grpThreads = (gridDim.x >> 3) * blockDim.x;
    const int lo = r * NODES_PER_XCD;
    const int hi = (lo + NODES_PER_XCD < NN) ? lo + NODES_PER_XCD : NN;
    const int4* d4 = (const int4*)(ei + EE);
    for (int q = bi * blockDim.x + threadIdx.x; q < EE / 4; q += grpThreads) {
        int4 d = d4[q];
        if (d.x >= lo && d.x < hi) atomicAdd(&cnt[d.x], 1);
        if (d.y >= lo && d.y < hi) atomicAdd(&cnt[d.y], 1);
        if (d.z >= lo && d.z < hi) atomicAdd(&cnt[d.z], 1);
        if (d.w >= lo && d.w < hi) atomicAdd(&cnt[d.w], 1);
    }
}

__global__ void scatter_x(const int* __restrict__ ei, int* __restrict__ fill,
                          int* __restrict__ colA) {
    const int r = blockIdx.x & 7;
    const int bi = blockIdx.x >> 3;
    const int grpThreads = (gridDim.x >> 3) * blockDim.x;
    const int lo = r * NODES_PER_XCD;
    const int hi = (lo + NODES_PER_XCD < NN) ? lo + NODES_PER_XCD : NN;
    const int4* d4 = (const int4*)(ei + EE);
    const int4* s4 = (const int4*)ei;
    for (int q = bi * blockDim.x + threadIdx.x; q < EE / 4; q += grpThreads) {
        int4 d = d4[q];
        int4 s = s4[q];
        if (d.x >= lo && d.x < hi) colA[atomicAdd(&fill[d.x], 1)] = s.x;
        if (d.y >= lo && d.y < hi) colA[atomicAdd(&fill[d.y], 1)] = s.y;
        if (d.z >= lo && d.z < hi) colA[atomicAdd(&fill[d.z], 1)] = s.z;
        if (d.w >= lo && d.w < hi) colA[atomicAdd(&fill[d.w], 1)] = s.w;
    }
}

// ---------------- prefix scan over cnt -> rowptr, dinv, fill cursors ----------------

__global__ void scanA(const int* __restrict__ cnt, int* __restrict__ bsum) {
    __shared__ int ls[SCAN_BLK];
    int t = threadIdx.x;
    int base = blockIdx.x * SCAN_ITEMS + t * 4;
    int s = 0;
#pragma unroll
    for (int k = 0; k < 4; ++k) { int i = base + k; if (i < NN) s += cnt[i]; }
    ls[t] = s; __syncthreads();
    for (int off = 128; off > 0; off >>= 1) {
        if (t < off) ls[t] += ls[t + off];
        __syncthreads();
    }
    if (t == 0) bsum[blockIdx.x] = ls[0];
}

__global__ void scanB(const int* __restrict__ bsum, int* __restrict__ boff) {
    __shared__ int ls[SCAN_BLK];
    int t = threadIdx.x;
    int v = (t < NSCANBLK) ? bsum[t] : 0;
    ls[t] = v; __syncthreads();
    for (int off = 1; off < SCAN_BLK; off <<= 1) {
        int x = 0;
        if (t >= off) x = ls[t - off];
        __syncthreads();
        ls[t] += x;
        __syncthreads();
    }
    if (t < NSCANBLK) boff[t] = ls[t] - v;  // exclusive
}

__global__ void scanC(int* __restrict__ cnt /* becomes fill-start */, const int* __restrict__ boff,
                      int* __restrict__ rowptr, float* __restrict__ dinv) {
    __shared__ int ls[SCAN_BLK];
    int t = threadIdx.x;
    int base = blockIdx.x * SCAN_ITEMS + t * 4;
    int c[4]; int s = 0;
#pragma unroll
    for (int k = 0; k < 4; ++k) { int i = base + k; c[k] = (i < NN) ? cnt[i] : 0; s += c[k]; }
    ls[t] = s; __syncthreads();
    for (int off = 1; off < SCAN_BLK; off <<= 1) {
        int x = 0;
        if (t >= off) x = ls[t - off];
        __syncthreads();
        ls[t] += x;
        __syncthreads();
    }
    int run = boff[blockIdx.x] + ls[t] - s;  // exclusive base for this thread
#pragma unroll
    for (int k = 0; k < 4; ++k) {
        int i = base + k;
        if (i < NN) {
            rowptr[i] = run;
            cnt[i] = run;  // fill cursor for scatter
            dinv[i] = rsqrtf((float)(c[k] + 1));  // +1 self-loop
            run += c[k];
            if (i == NN - 1) rowptr[NN] = run;
        }
    }
}

// ---------------- x pre-scale: xsc[n][k] = half(x[n][k] * dinv[n]), 20 ch tight ----------------

__global__ void scale_x(const float* __restrict__ x, const float* __restrict__ dinv,
                        __half* __restrict__ xsc) {
    int idx = blockIdx.x * blockDim.x + threadIdx.x;
    if (idx < NN * 20) {
        int n = idx / 20;
        xsc[idx] = __float2half(x[idx] * dinv[n]);
    }
}

// ---------------- GEMM: optional BN-affine+ReLU on input; two epilogues ----------------
// SCALED=true : outH[node*FOUT+c] = half(acc * dinv[node])   (pre-aggregation form)
// SCALED=false: outF[node*FOUT+c] = acc + bias[c]            (post-aggregation form, layer 1)

template <int FIN, int FOUT, bool AFFINE, bool SCALED>
__global__ void gemm_k(const float* __restrict__ hin, const float* __restrict__ aArr,
                       const float* __restrict__ bArr, const float* __restrict__ W,
                       const float* __restrict__ dinv, const float* __restrict__ bias,
                       float* __restrict__ outF, __half* __restrict__ outH) {
    constexpr int NB = 256 / FOUT;  // nodes per group
    __shared__ float Wl[FIN * FOUT];
    __shared__ float rows[NB][FIN];
    const int t = threadIdx.x;
    for (int i = t; i < FIN * FOUT; i += 256) Wl[i] = W[i];
    const int c = t % FOUT, s = t / FOUT;
    const int ngrp = (NN + NB - 1) / NB;
    for (int grp = blockIdx.x; grp < ngrp; grp += gridDim.x) {
        __syncthreads();  // covers Wl on first iter; protects rows reuse after
        for (int i = t; i < NB * FIN; i += 256) {
            int sn = i / FIN, k = i % FIN;
            int n2 = grp * NB + sn;
            float v = 0.f;
            if (n2 < NN) {
                v = hin[(size_t)n2 * FIN + k];
                if constexpr (AFFINE) {
                    v = aArr[k] * v + bArr[k];
                    v = v > 0.f ? v : 0.f;
                }
            }
            rows[sn][k] = v;
        }
        __syncthreads();
        int node = grp * NB + s;
        if (node < NN) {
            float acc = 0.f;
#pragma unroll
            for (int k = 0; k < FIN; ++k) acc += rows[s][k] * Wl[k * FOUT + c];
            if constexpr (SCALED)
                outH[(size_t)node * FOUT + c] = __float2half(acc * dinv[node]);
            else
                outF[(size_t)node * FOUT + c] = acc + bias[c];
        }
    }
}

// ---------------- gather aggregation from fp16 source ----------------
// src rows are H2 half2 wide; out[i] = dinv[i]*(src[i] + sum_nbr src[j]) (+ bias), fp32,
// out row stride = OUTF floats. H2 need not divide 64 (tail lanes idle).

template <int H2, int OUTF>
__global__ void agg_half(const __half2* __restrict__ src, const int* __restrict__ rowptr,
                         const int* __restrict__ colA, const float* __restrict__ dinv,
                         const float* __restrict__ bias, float* __restrict__ out) {
    constexpr int SUB = 64 / H2;
    const int lane = threadIdx.x & 63;
    const int wid = (blockIdx.x * blockDim.x + threadIdx.x) >> 6;
    const int totalWaves = (gridDim.x * blockDim.x) >> 6;
    const int f = lane % H2;
    const int sub = lane / H2;
    const int stride = totalWaves * SUB;
    float bx = 0.f, by = 0.f;
    if (bias != nullptr) {
        bx = bias[2 * f];
        by = (2 * f + 1 < OUTF) ? bias[2 * f + 1] : 0.f;
    }
    const int i0 = (sub < SUB) ? wid * SUB + sub : NN;  // idle tail lanes skip
    for (int i = i0; i < NN; i += stride) {
        const int r0 = rowptr[i], r1 = rowptr[i + 1];
        float2 acc = __half22float2(src[(size_t)i * H2 + f]);  // self loop (pre-scaled by dinv[i])
        float2 acc2 = {0.f, 0.f};
        int e = r0;
        for (; e + 3 < r1; e += 4) {
            int j0 = colA[e], j1 = colA[e + 1], j2 = colA[e + 2], j3 = colA[e + 3];
            float2 v0 = __half22float2(src[(size_t)j0 * H2 + f]);
            float2 v1 = __half22float2(src[(size_t)j1 * H2 + f]);
            float2 v2 = __half22float2(src[(size_t)j2 * H2 + f]);
            float2 v3 = __half22float2(src[(size_t)j3 * H2 + f]);
            acc.x += v0.x + v1.x;
            acc.y += v0.y + v1.y;
            acc2.x += v2.x + v3.x;
            acc2.y += v2.y + v3.y;
        }
        for (; e < r1; ++e) {
            float2 v = __half22float2(src[(size_t)colA[e] * H2 + f]);
            acc.x += v.x; acc.y += v.y;
        }
        acc.x += acc2.x; acc.y += acc2.y;
        const float d = dinv[i];
        out[(size_t)i * OUTF + 2 * f] = d * acc.x + bx;
        if (2 * f + 1 < OUTF) out[(size_t)i * OUTF + 2 * f + 1] = d * acc.y + by;
    }
}

// ---------------- BN stats ----------------

template <int F>
__global__ void bn_stats(const float* __restrict__ h, float* __restrict__ sums,
                         float* __restrict__ ssq) {
    __shared__ float ls[F], lq[F];
    const int t = threadIdx.x;
    const int c = t % F;
    constexpr int ROWS = 256 / F;
    float s = 0.f, q = 0.f;
    for (int n = blockIdx.x * ROWS + t / F; n < NN; n += gridDim.x * ROWS) {
        float v = h[(size_t)n * F + c];
        s += v; q += v * v;
    }
    if (t < F) { ls[t] = 0.f; lq[t] = 0.f; }
    __syncthreads();
    atomicAdd(&ls[c], s);
    atomicAdd(&lq[c], q);
    __syncthreads();
    if (t < F) { atomicAdd(&sums[t], ls[t]); atomicAdd(&ssq[t], lq[t]); }
}

template <int F>
__global__ void bn_finalize(const float* __restrict__ sums, const float* __restrict__ ssq,
                            const float* __restrict__ g, const float* __restrict__ be,
                            float* __restrict__ aArr, float* __restrict__ bArr) {
    int c = threadIdx.x;
    if (c < F) {
        float mu = sums[c] / (float)NN;
        float var = ssq[c] / (float)NN - mu * mu;
        float a = g[c] * rsqrtf(var + BNEPS);
        aArr[c] = a;
        bArr[c] = be[c] - mu * a;
    }
}

// ---------------- GAT: xg = relu(bn(h3)) @ Wg (fp16) ; a_src/a_dst (fp32) ----------------

__global__ void gat_pre(const float* __restrict__ out3, const float* __restrict__ aArr,
                        const float* __restrict__ bArr, const float* __restrict__ Wg,
                        const float* __restrict__ att_src, const float* __restrict__ att_dst,
                        __half* __restrict__ xg, float* __restrict__ asrc,
                        float* __restrict__ adst) {
    __shared__ float Wl[16 * 128];
    __shared__ float row[2][16];
    __shared__ float red[2][128];
    const int t = threadIdx.x;
    for (int i = t; i < 16 * 128; i += 256) Wl[i] = Wg[i];
    const int c = t & 127, s = t >> 7;
    const float atts = att_src[c], attd = att_dst[c];
    const int h = c >> 4;
    const int cc = c & 15;
    const int ngrp = (NN + 1) / 2;
    for (int grp = blockIdx.x; grp < ngrp; grp += gridDim.x) {
        __syncthreads();
        if (t < 32) {
            int sn = t >> 4, k = t & 15;
            int n2 = grp * 2 + sn;
            float v = 0.f;
            if (n2 < NN) {
                v = out3[n2 * 16 + k];
                v = aArr[k] * v + bArr[k];
                v = v > 0.f ? v : 0.f;
            }
            row[sn][k] = v;
        }
        __syncthreads();
        float acc = 0.f;
#pragma unroll
        for (int k = 0; k < 16; ++k) acc += row[s][k] * Wl[k * 128 + c];
        int node = grp * 2 + s;
        if (node < NN) xg[(size_t)node * 128 + c] = __float2half(acc);
        red[s][c] = acc * atts;
        __syncthreads();
        if (cc == 0 && node < NN) {
            float v = 0.f;
#pragma unroll
            for (int k2 = 0; k2 < 16; ++k2) v += red[s][h * 16 + k2];
            asrc[node * 8 + h] = v;
        }
        __syncthreads();
        red[s][c] = acc * attd;
        __syncthreads();
        if (cc == 0 && node < NN) {
            float v = 0.f;
#pragma unroll
            for (int k2 = 0; k2 < 16; ++k2) v += red[s][h * 16 + k2];
            adst[node * 8 + h] = v;
        }
    }
}

// ---------------- GAT single-pass: unnormalized accumulate, divide at end ----------------

__device__ __forceinline__ float leaky02(float x) { return x > 0.f ? x : 0.2f * x; }

__global__ void gat_agg3(const __half2* __restrict__ xg2, const float* __restrict__ asrc,
                         const float* __restrict__ adst, const int* __restrict__ rowptr,
                         const int* __restrict__ colA, const float* __restrict__ bg,
                         float* __restrict__ hg) {
    const int lane = threadIdx.x & 63;
    const int wid = (blockIdx.x * blockDim.x + threadIdx.x) >> 6;
    const int totalWaves = (gridDim.x * blockDim.x) >> 6;
    const int head = lane >> 3;  // lane holds channel pair `lane`; head = lane/8
    for (int i = wid; i < NN; i += totalWaves) {
        const int r0 = rowptr[i], r1 = rowptr[i + 1];
        const float adh = adst[i * 8 + head];
        // self-loop
        float ssum;
        float2 acc, acc2 = {0.f, 0.f};
        {
            float w = __expf(leaky02(asrc[i * 8 + head] + adh));
            float2 v = __half22float2(xg2[(size_t)i * 64 + lane]);
            acc.x = w * v.x;
            acc.y = w * v.y;
            ssum = w;
        }
        int e = r0;
        for (; e + 3 < r1; e += 4) {
            int j0 = colA[e], j1 = colA[e + 1], j2 = colA[e + 2], j3 = colA[e + 3];
            float a0 = asrc[j0 * 8 + head];
            float a1 = asrc[j1 * 8 + head];
            float a2 = asrc[j2 * 8 + head];
            float a3 = asrc[j3 * 8 + head];
            float2 v0 = __half22float2(xg2[(size_t)j0 * 64 + lane]);
            float2 v1 = __half22float2(xg2[(size_t)j1 * 64 + lane]);
            float2 v2 = __half22float2(xg2[(size_t)j2 * 64 + lane]);
            float2 v3 = __half22float2(xg2[(size_t)j3 * 64 + lane]);
            float w0 = __expf(leaky02(a0 + adh));
            float w1 = __expf(leaky02(a1 + adh));
            float w2 = __expf(leaky02(a2 + adh));
            float w3 = __expf(leaky02(a3 + adh));
            acc.x += w0 * v0.x + w1 * v1.x;
            acc.y += w0 * v0.y + w1 * v1.y;
            acc2.x += w2 * v2.x + w3 * v3.x;
            acc2.y += w2 * v2.y + w3 * v3.y;
            ssum += (w0 + w1) + (w2 + w3);
        }
        for (; e < r1; ++e) {
            int j = colA[e];
            float w = __expf(leaky02(asrc[j * 8 + head] + adh));
            float2 v = __half22float2(xg2[(size_t)j * 64 + lane]);
            acc.x += w * v.x;
            acc.y += w * v.y;
            ssum += w;
        }
        const float inv = 1.f / ssum;
        acc.x = (acc.x + acc2.x) * inv;
        acc.y = (acc.y + acc2.y) * inv;
        // reduce over heads: lanes {l, l^8, l^16, l^32} share channel pair (lane&7)
#pragma unroll
        for (int off = 8; off < 64; off <<= 1) {
            acc.x += __shfl_xor(acc.x, off);
            acc.y += __shfl_xor(acc.y, off);
        }
        if (lane < 8) {
            hg[i * 16 + 2 * lane] = acc.x * 0.125f + bg[2 * lane];
            hg[i * 16 + 2 * lane + 1] = acc.y * 0.125f + bg[2 * lane + 1];
        }
    }
}

// ---------------- pool + final ----------------

__global__ void pool_kernel(const float* __restrict__ hg, const int* __restrict__ batch,
                            float* __restrict__ pooled) {
    int idx = blockIdx.x * blockDim.x + threadIdx.x;
    if (idx < NN * 16) {
        int n = idx >> 4, c = idx & 15;
        atomicAdd(&pooled[batch[n] * 16 + c], hg[idx]);
    }
}

__global__ void final_kernel(const float* __restrict__ pooled, const float* __restrict__ Wf,
                             const float* __restrict__ bf, float* __restrict__ out) {
    int idx = blockIdx.x * blockDim.x + threadIdx.x;
    if (idx < GG * 3) {
        int g = idx / 3, j = idx - g * 3;
        float acc = bf[j];
#pragma unroll
        for (int c = 0; c < 16; ++c) acc += pooled[g * 16 + c] * Wf[c * 3 + j];
        out[idx] = acc;
    }
}

// ---------------- launcher ----------------

extern "C" void kernel_launch(void* const* d_in, const int* in_sizes, int n_in,
                              void* d_out, int out_size, void* d_ws, size_t ws_size,
                              hipStream_t stream) {
    const float* x = (const float*)d_in[0];
    const int* ei = (const int*)d_in[1];
    const int* batch = (const int*)d_in[2];
    const float* W1 = (const float*)d_in[3];  const float* b1 = (const float*)d_in[4];
    const float* g1 = (const float*)d_in[5];  const float* be1 = (const float*)d_in[6];
    const float* W2 = (const float*)d_in[7];  const float* b2 = (const float*)d_in[8];
    const float* g2 = (const float*)d_in[9];  const float* be2 = (const float*)d_in[10];
    const float* W3 = (const float*)d_in[11]; const float* b3 = (const float*)d_in[12];
    const float* g3 = (const float*)d_in[13]; const float* be3 = (const float*)d_in[14];
    const float* Wg = (const float*)d_in[15];
    const float* att_src = (const float*)d_in[16];
    const float* att_dst = (const float*)d_in[17];
    const float* bg = (const float*)d_in[18];
    const float* Wf = (const float*)d_in[19];
    const float* bf = (const float*)d_in[20];
    float* out = (float*)d_out;

    char* w = (char*)d_ws;
    auto alloc = [&](size_t bytes) -> char* {
        char* p = w;
        w += (bytes + 255) & ~(size_t)255;
        return p;
    };
    // --- zeroed region (one memset) ---
    int* fill = (int*)alloc((size_t)NN * 4);
    float* pooled = (float*)alloc((size_t)GG * 16 * 4);
    float* sums1 = (float*)alloc(64 * 4); float* ssq1 = (float*)alloc(64 * 4);
    float* sums2 = (float*)alloc(32 * 4); float* ssq2 = (float*)alloc(32 * 4);
    float* sums3 = (float*)alloc(16 * 4); float* ssq3 = (float*)alloc(16 * 4);
    size_t zeroBytes = (size_t)(w - (char*)d_ws);
    // --- rest ---
    float* a1 = (float*)alloc(64 * 4); float* bh1 = (float*)alloc(64 * 4);
    float* a2 = (float*)alloc(32 * 4); float* bh2 = (float*)alloc(32 * 4);
    float* a3 = (float*)alloc(16 * 4); float* bh3 = (float*)alloc(16 * 4);
    int* bsum = (int*)alloc(128 * 4);
    int* boff = (int*)alloc(128 * 4);
    int* rowptr = (int*)alloc((size_t)(NN + 1) * 4);
    int* colA = (int*)alloc((size_t)EE * 4);
    float* dinv = (float*)alloc((size_t)NN * 4);
    char* A = alloc((size_t)NN * 64 * 4);  // 25.6 MB scratch block A
    char* B = alloc((size_t)NN * 64 * 4);  // 25.6 MB scratch block B

    // lifetime-based aliases
    __half* xsc  = (__half*)B;                               // [NN,20] fp16   4.0 MB
    float*  aggx = (float*)(B + (size_t)NN * 32 * 2);        // [NN,20] fp32   8.0 MB
    float*  h1   = (float*)A;                                // [NN,64] fp32  25.6 MB
    __half* hs2  = (__half*)B;                               // [NN,32] fp16   6.4 MB
    float*  h2   = (float*)(B + (size_t)NN * 32 * 2);        // [NN,32] fp32  12.8 MB
    __half* hs3  = (__half*)A;                               // [NN,16] fp16   3.2 MB
    float*  h3   = (float*)(A + (size_t)NN * 16 * 2);        // [NN,16] fp32   6.4 MB
    __half* xgh  = (__half*)B;                               // [NN,128] fp16 25.6 MB
    float*  asrc = (float*)(A + (size_t)NN * 24 * 4);        // [NN,8]  fp32   3.2 MB
    float*  adst = (float*)(A + (size_t)NN * 32 * 4);        // [NN,8]  fp32   3.2 MB
    float*  hg   = (float*)(A + (size_t)NN * 40 * 4);        // [NN,16] fp32   6.4 MB

    hipMemsetAsync(d_ws, 0, zeroBytes, stream);

    count_x<<<2048, 256, 0, stream>>>(ei, fill);
    scanA<<<NSCANBLK, SCAN_BLK, 0, stream>>>(fill, bsum);
    scanB<<<1, SCAN_BLK, 0, stream>>>(bsum, boff);
    scanC<<<NSCANBLK, SCAN_BLK, 0, stream>>>(fill, boff, rowptr, dinv);
    scatter_x<<<2048, 256, 0, stream>>>(ei, fill, colA);

    // layer 1: aggregate x first (20ch tight fp16), then GEMM 20->64 (+b1)
    scale_x<<<(NN * 20 + 255) / 256, 256, 0, stream>>>(x, dinv, xsc);
    agg_half<10, 20><<<2048, 256, 0, stream>>>((const __half2*)xsc, rowptr, colA, dinv, nullptr, aggx);
    gemm_k<20, 64, false, false><<<2048, 256, 0, stream>>>(aggx, nullptr, nullptr, W1, dinv, b1, h1, nullptr);
    bn_stats<64><<<512, 256, 0, stream>>>(h1, sums1, ssq1);
    bn_finalize<64><<<1, 64, 0, stream>>>(sums1, ssq1, g1, be1, a1, bh1);

    // layer 2: 64 -> 32 (fp16 pre-agg buffer)
    gemm_k<64, 32, true, true><<<2048, 256, 0, stream>>>(h1, a1, bh1, W2, dinv, nullptr, nullptr, hs2);
    agg_half<16, 32><<<2048, 256, 0, stream>>>((const __half2*)hs2, rowptr, colA, dinv, b2, h2);
    bn_stats<32><<<512, 256, 0, stream>>>(h2, sums2, ssq2);
    bn_finalize<32><<<1, 64, 0, stream>>>(sums2, ssq2, g2, be2, a2, bh2);

    // layer 3: 32 -> 16 (fp16 pre-agg buffer)
    gemm_k<32, 16, true, true><<<2048, 256, 0, stream>>>(h2, a2, bh2, W3, dinv, nullptr, nullptr, hs3);
    agg_half<8, 16><<<2048, 256, 0, stream>>>((const __half2*)hs3, rowptr, colA, dinv, b3, h3);
    bn_stats<16><<<512, 256, 0, stream>>>(h3, sums3, ssq3);
    bn_finalize<16><<<1, 64, 0, stream>>>(sums3, ssq3, g3, be3, a3, bh3);

    // GAT (fp16 xg), single-pass softmax+aggregate
    gat_pre<<<2048, 256, 0, stream>>>(h3, a3, bh3, Wg, att_src, att_dst, xgh, asrc, adst);
    gat_agg3<<<2048, 256, 0, stream>>>((const __half2*)xgh, asrc, adst, rowptr, colA, bg, hg);

    // pool + classify
    pool_kernel<<<(NN * 16 + 255) / 256, 256, 0, stream>>>(hg, batch, pooled);
    final_kernel<<<(GG * 3 + 255) / 256, 256, 0, stream>>>(pooled, Wf, bf, out);
}